// Round 1
// baseline (6263.214 us; speedup 1.0000x reference)
//
#include <hip/hip_runtime.h>

// Codred forward: span-pool -> pairwise relation -> 4-layer transformer over
// 1600 relation tokens -> (h,t) gather -> 97-way logits, bag max.
// Round 0: correctness-first full fp32 implementation.
//   - tiled fp32 GEMM (64x64x16, fused bias + optional relu)
//   - exact softmax attention, one block per (query token, head)
//   - fused residual + LayerNorm
// Future: bf16 MFMA GEMMs + fused attention (threshold 2.95e-2 permits bf16).

#define D    768
#define H    8
#define DKD  96
#define LAY  4
#define FFD  1024
#define NREL 97
#define BAG  8
#define SPANS 5
#define E    40
#define TT   1600   // E*E tokens
#define SEQ  512

// ---------------- block-wide reductions (256 threads = 4 waves) -------------
__device__ __forceinline__ float block_max(float v, float* red) {
#pragma unroll
    for (int o = 32; o >= 1; o >>= 1) v = fmaxf(v, __shfl_xor(v, o));
    __syncthreads();                       // protect prior use of red
    if ((threadIdx.x & 63) == 0) red[threadIdx.x >> 6] = v;
    __syncthreads();
    return fmaxf(fmaxf(red[0], red[1]), fmaxf(red[2], red[3]));
}
__device__ __forceinline__ float block_sum(float v, float* red) {
#pragma unroll
    for (int o = 32; o >= 1; o >>= 1) v += __shfl_xor(v, o);
    __syncthreads();
    if ((threadIdx.x & 63) == 0) red[threadIdx.x >> 6] = v;
    __syncthreads();
    return red[0] + red[1] + red[2] + red[3];
}

// ---------------- span max-pool: htb[e][d] = max over [st,en] ---------------
__global__ __launch_bounds__(256) void span_pool(const float* __restrict__ emb,
        const int* __restrict__ spans, float* __restrict__ htb) {
    const int e = blockIdx.x;              // 0..39, e = bag*SPANS + span
    const int bag = e / SPANS;
    const int st = spans[e * 2 + 0];
    const int en = spans[e * 2 + 1];
    const int tid = threadIdx.x;
#pragma unroll
    for (int i = 0; i < 3; ++i) {
        const int dcol = tid + i * 256;
        float m = -1e30f;
        for (int p = st; p <= en; ++p)
            m = fmaxf(m, emb[((size_t)bag * SEQ + p) * D + dcol]);
        htb[(size_t)e * D + dcol] = m;
    }
}

// ---------------- alpha[i*E+j][d] = relu(u[i][d] + v[j][d]) -----------------
__global__ __launch_bounds__(256) void alpha_k(const float* __restrict__ u,
        const float* __restrict__ v, float* __restrict__ a) {
    const int ij = blockIdx.x;             // 0..1599
    const int i = ij / E, j = ij % E;
    const int tid = threadIdx.x;
#pragma unroll
    for (int t2 = 0; t2 < 3; ++t2) {
        const int d = tid + t2 * 256;
        a[(size_t)ij * D + d] = fmaxf(u[(size_t)i * D + d] + v[(size_t)j * D + d], 0.f);
    }
}

// ---------------- tiled fp32 GEMM: C = A[M,K] @ B[K,N] + bias ---------------
// 64x64 tile, BK=16, 256 threads, 4x4 micro-tile per thread.
template<int RELU>
__global__ __launch_bounds__(256) void gemm_f32(const float* __restrict__ A,
        const float* __restrict__ B, const float* __restrict__ bias,
        float* __restrict__ C, int M, int N, int K) {
    __shared__ float As[16][68];           // As[k][m], +4 pad keeps 16B align
    __shared__ float Bs[16][68];           // Bs[k][n]
    const int bn = blockIdx.x * 64;
    const int bm = blockIdx.y * 64;
    const int tid = threadIdx.x;
    const int tx = tid & 15;
    const int ty = tid >> 4;
    const int ar = tid >> 2;               // A tile: 64 rows x 16 k
    const int ac = (tid & 3) << 2;
    const int br = tid >> 4;               // B tile: 16 k x 64 cols
    const int bc = (tid & 15) << 2;
    float acc[4][4] = {};
    for (int k0 = 0; k0 < K; k0 += 16) {
        float4 av;
        if (bm + ar < M) av = *(const float4*)(A + (size_t)(bm + ar) * K + k0 + ac);
        else             av = make_float4(0.f, 0.f, 0.f, 0.f);
        const float4 bv = *(const float4*)(B + (size_t)(k0 + br) * N + bn + bc);
        As[ac + 0][ar] = av.x; As[ac + 1][ar] = av.y;
        As[ac + 2][ar] = av.z; As[ac + 3][ar] = av.w;
        *(float4*)&Bs[br][bc] = bv;
        __syncthreads();
#pragma unroll
        for (int kk = 0; kk < 16; ++kk) {
            const float4 a = *(const float4*)&As[kk][ty << 2];
            const float4 b = *(const float4*)&Bs[kk][tx << 2];
            acc[0][0] += a.x * b.x; acc[0][1] += a.x * b.y; acc[0][2] += a.x * b.z; acc[0][3] += a.x * b.w;
            acc[1][0] += a.y * b.x; acc[1][1] += a.y * b.y; acc[1][2] += a.y * b.z; acc[1][3] += a.y * b.w;
            acc[2][0] += a.z * b.x; acc[2][1] += a.z * b.y; acc[2][2] += a.z * b.z; acc[2][3] += a.z * b.w;
            acc[3][0] += a.w * b.x; acc[3][1] += a.w * b.y; acc[3][2] += a.w * b.z; acc[3][3] += a.w * b.w;
        }
        __syncthreads();
    }
#pragma unroll
    for (int i = 0; i < 4; ++i) {
        const int row = bm + (ty << 2) + i;
        if (row >= M) continue;
#pragma unroll
        for (int j = 0; j < 4; ++j) {
            const int col = bn + (tx << 2) + j;
            float val = acc[i][j] + bias[col];
            if (RELU) val = fmaxf(val, 0.f);
            C[(size_t)row * N + col] = val;
        }
    }
}

// ---------------- exact attention: one block per (token t, head h) ----------
__global__ __launch_bounds__(256) void attn_f32(const float* __restrict__ q,
        const float* __restrict__ k, const float* __restrict__ v,
        float* __restrict__ o) {
    __shared__ float sc[TT];
    __shared__ float qs[DKD];
    __shared__ float red[4];
    __shared__ float opart[2][DKD];
    const int t = blockIdx.x;
    const int h = blockIdx.y;
    const int tid = threadIdx.x;
    const float scale = 0.10206207261596577f;   // 1/sqrt(96)
    if (tid < DKD) qs[tid] = q[(size_t)t * D + h * DKD + tid];
    __syncthreads();
    // scores
    for (int s = tid; s < TT; s += 256) {
        const float* kp = k + (size_t)s * D + h * DKD;
        float acc = 0.f;
#pragma unroll
        for (int d = 0; d < DKD; d += 4) {
            const float4 kv = *(const float4*)(kp + d);
            acc += qs[d] * kv.x + qs[d + 1] * kv.y + qs[d + 2] * kv.z + qs[d + 3] * kv.w;
        }
        sc[s] = acc * scale;
    }
    __syncthreads();
    float m = -1e30f;
    for (int s = tid; s < TT; s += 256) m = fmaxf(m, sc[s]);
    m = block_max(m, red);
    float ls = 0.f;
    for (int s = tid; s < TT; s += 256) { const float e = __expf(sc[s] - m); sc[s] = e; ls += e; }
    const float inv = 1.f / block_sum(ls, red);   // sync inside makes sc[] visible
    // output: two s-halves, 96 dims each (192 active threads)
    const int g = tid / DKD;
    const int d = tid % DKD;
    if (g < 2) {
        float acc = 0.f;
        const int s0 = g * (TT / 2), s1 = s0 + TT / 2;
        for (int s = s0; s < s1; ++s) acc += sc[s] * v[(size_t)s * D + h * DKD + d];
        opart[g][d] = acc;
    }
    __syncthreads();
    if (tid < DKD) o[(size_t)t * D + h * DKD + tid] = (opart[0][tid] + opart[1][tid]) * inv;
}

// ---------------- x = LayerNorm(x + y) * g + b (in-place on x) --------------
__global__ __launch_bounds__(256) void add_ln(float* __restrict__ x,
        const float* __restrict__ y, const float* __restrict__ g,
        const float* __restrict__ b) {
    __shared__ float red[4];
    const int row = blockIdx.x;
    const int tid = threadIdx.x;
    float vals[3];
    float s = 0.f;
#pragma unroll
    for (int i = 0; i < 3; ++i) {
        const int c = tid + i * 256;
        const float t = x[(size_t)row * D + c] + y[(size_t)row * D + c];
        vals[i] = t; s += t;
    }
    const float mean = block_sum(s, red) * (1.f / 768.f);
    float s2 = 0.f;
#pragma unroll
    for (int i = 0; i < 3; ++i) { const float dd = vals[i] - mean; s2 += dd * dd; }
    const float var = block_sum(s2, red) * (1.f / 768.f);
    const float inv = rsqrtf(var + 1e-5f);
#pragma unroll
    for (int i = 0; i < 3; ++i) {
        const int c = tid + i * 256;
        x[(size_t)row * D + c] = (vals[i] - mean) * inv * g[c] + b[c];
    }
}

// ---------------- predictor: out[r] = max_bag(ht_feat[bag] . pw[:,r]) + pb --
__global__ __launch_bounds__(256) void predict_k(const float* __restrict__ x,
        const float* __restrict__ pw, const float* __restrict__ pb,
        float* __restrict__ out) {
    __shared__ float red[4];
    const int r = blockIdx.x;
    const int tid = threadIdx.x;
    float best = -1e30f;
    for (int bag = 0; bag < BAG; ++bag) {
        const int row = (bag * SPANS) * E + (bag * SPANS + 1);
        const float* f = x + (size_t)row * D;
        float acc = 0.f;
        for (int d = tid; d < D; d += 256) acc += f[d] * pw[(size_t)d * NREL + r];
        best = fmaxf(best, block_sum(acc, red));
    }
    if (tid == 0) out[r] = best + pb[r];
}

extern "C" void kernel_launch(void* const* d_in, const int* in_sizes, int n_in,
                              void* d_out, int out_size, void* d_ws, size_t ws_size,
                              hipStream_t stream) {
    const float* emb  = (const float*)d_in[0];
    const int*  spans = (const int*)d_in[1];
    const float* wu_w = (const float*)d_in[2];  const float* wu_b = (const float*)d_in[3];
    const float* wvv_w= (const float*)d_in[4];  const float* wvv_b= (const float*)d_in[5];
    const float* lnr_w= (const float*)d_in[6];  const float* lnr_b= (const float*)d_in[7];
    const float* wq = (const float*)d_in[8];    const float* bq = (const float*)d_in[9];
    const float* wk = (const float*)d_in[10];   const float* bk = (const float*)d_in[11];
    const float* wv = (const float*)d_in[12];   const float* bv = (const float*)d_in[13];
    const float* wo = (const float*)d_in[14];   const float* bo = (const float*)d_in[15];
    const float* w1 = (const float*)d_in[16];   const float* b1 = (const float*)d_in[17];
    const float* w2 = (const float*)d_in[18];   const float* b2 = (const float*)d_in[19];
    const float* g1 = (const float*)d_in[20];   const float* be1= (const float*)d_in[21];
    const float* g2 = (const float*)d_in[22];   const float* be2= (const float*)d_in[23];
    const float* pw = (const float*)d_in[24];   const float* pb = (const float*)d_in[25];

    // workspace layout (floats); total ~36.4 MB
    float* ws  = (float*)d_ws;
    float* htb = ws;                    // E*D
    float* ub  = htb + E * D;           // E*D
    float* vb  = ub + E * D;            // E*D
    float* xb  = vb + E * D;            // TT*D  (token stream)
    float* tb  = xb + TT * D;           // TT*D  (alpha, then GEMM tmp)
    float* qb  = tb + TT * D;           // TT*D
    float* kb  = qb + TT * D;           // TT*D
    float* vvb = kb + TT * D;           // TT*D
    float* ob  = vvb + TT * D;          // TT*D
    float* fb  = ob + TT * D;           // TT*FFD

    span_pool<<<E, 256, 0, stream>>>(emb, spans, htb);
    gemm_f32<0><<<dim3(D / 64, 1), 256, 0, stream>>>(htb, wu_w, wu_b, ub, E, D, D);
    gemm_f32<0><<<dim3(D / 64, 1), 256, 0, stream>>>(htb, wvv_w, wvv_b, vb, E, D, D);
    alpha_k<<<TT, 256, 0, stream>>>(ub, vb, tb);
    gemm_f32<1><<<dim3(D / 64, TT / 64), 256, 0, stream>>>(tb, lnr_w, lnr_b, xb, TT, D, D);

    for (int l = 0; l < LAY; ++l) {
        gemm_f32<0><<<dim3(D / 64, TT / 64), 256, 0, stream>>>(xb, wq + (size_t)l * D * D, bq + l * D, qb, TT, D, D);
        gemm_f32<0><<<dim3(D / 64, TT / 64), 256, 0, stream>>>(xb, wk + (size_t)l * D * D, bk + l * D, kb, TT, D, D);
        gemm_f32<0><<<dim3(D / 64, TT / 64), 256, 0, stream>>>(xb, wv + (size_t)l * D * D, bv + l * D, vvb, TT, D, D);
        attn_f32<<<dim3(TT, H), 256, 0, stream>>>(qb, kb, vvb, ob);
        gemm_f32<0><<<dim3(D / 64, TT / 64), 256, 0, stream>>>(ob, wo + (size_t)l * D * D, bo + l * D, tb, TT, D, D);
        add_ln<<<TT, 256, 0, stream>>>(xb, tb, g1 + l * D, be1 + l * D);
        gemm_f32<1><<<dim3(FFD / 64, TT / 64), 256, 0, stream>>>(xb, w1 + (size_t)l * D * FFD, b1 + l * FFD, fb, TT, FFD, D);
        gemm_f32<0><<<dim3(D / 64, TT / 64), 256, 0, stream>>>(fb, w2 + (size_t)l * FFD * D, b2 + l * D, tb, TT, D, FFD);
        add_ln<<<TT, 256, 0, stream>>>(xb, tb, g2 + l * D, be2 + l * D);
    }

    predict_k<<<NREL, 256, 0, stream>>>(xb, pw, pb, (float*)d_out);
}

// Round 2
// 1311.381 us; speedup vs baseline: 4.7760x; 4.7760x over previous
//
#include <hip/hip_runtime.h>

// Codred forward. R1: bf16 MFMA GEMMs + flash-style MFMA attention.
//  - weights transposed+cast to bf16 [N][K] on device (per-layer buffer reuse)
//  - gemm_mfma: 128x64 tile, BK=32, 4 waves, 16x16x32 bf16 MFMA, fp32 accum,
//    fused bias (+relu), writes fp32 and/or bf16
//  - attn_mfma: block = (head, 64-query tile); K/V staged in LDS (V transposed
//    with XOR key-swizzle), online softmax in fp32, P via per-wave LDS
//  - residual/LayerNorm kept fp32 for accuracy; predictor fp32

#define D    768
#define H    8
#define DKD  96
#define LAY  4
#define FFD  1024
#define NREL 97
#define BAG  8
#define SPANS 5
#define E    40
#define TT   1600
#define SEQ  512

typedef __attribute__((ext_vector_type(8))) short bf16x8;
typedef __attribute__((ext_vector_type(4))) float f32x4;
typedef unsigned short ushort_t;
typedef unsigned int uint_t;

__device__ __forceinline__ ushort_t f2b(float x) {
    uint_t u = __builtin_bit_cast(uint_t, x);
    return (ushort_t)((u + 0x7fffu + ((u >> 16) & 1u)) >> 16);   // RNE
}
__device__ __forceinline__ float b2f(ushort_t v) {
    return __builtin_bit_cast(float, (uint_t)v << 16);
}

// ---------------- block reductions (256 thr) --------------------------------
__device__ __forceinline__ float block_sum(float v, float* red) {
#pragma unroll
    for (int o = 32; o >= 1; o >>= 1) v += __shfl_xor(v, o);
    __syncthreads();
    if ((threadIdx.x & 63) == 0) red[threadIdx.x >> 6] = v;
    __syncthreads();
    return red[0] + red[1] + red[2] + red[3];
}

// ---------------- span max-pool ---------------------------------------------
__global__ __launch_bounds__(256) void span_pool(const float* __restrict__ emb,
        const int* __restrict__ spans, float* __restrict__ htb) {
    const int e = blockIdx.x;
    const int bag = e / SPANS;
    const int st = spans[e * 2 + 0];
    const int en = spans[e * 2 + 1];
    const int tid = threadIdx.x;
#pragma unroll
    for (int i = 0; i < 3; ++i) {
        const int dcol = tid + i * 256;
        float m = -1e30f;
        for (int p = st; p <= en; ++p)
            m = fmaxf(m, emb[((size_t)bag * SEQ + p) * D + dcol]);
        htb[(size_t)e * D + dcol] = m;
    }
}

// ---------------- alpha (bf16 out) ------------------------------------------
__global__ __launch_bounds__(256) void alpha_k(const float* __restrict__ u,
        const float* __restrict__ v, ushort_t* __restrict__ a) {
    const int ij = blockIdx.x;
    const int i = ij / E, j = ij % E;
    const int tid = threadIdx.x;
#pragma unroll
    for (int t2 = 0; t2 < 3; ++t2) {
        const int d = tid + t2 * 256;
        a[(size_t)ij * D + d] = f2b(fmaxf(u[(size_t)i * D + d] + v[(size_t)j * D + d], 0.f));
    }
}

// ---------------- fp32 GEMM (small M paths: u,v) ----------------------------
template<int RELU>
__global__ __launch_bounds__(256) void gemm_f32(const float* __restrict__ A,
        const float* __restrict__ B, const float* __restrict__ bias,
        float* __restrict__ C, int M, int N, int K) {
    __shared__ float As[16][68];
    __shared__ float Bs[16][68];
    const int bn = blockIdx.x * 64;
    const int bm = blockIdx.y * 64;
    const int tid = threadIdx.x;
    const int tx = tid & 15;
    const int ty = tid >> 4;
    const int ar = tid >> 2;
    const int ac = (tid & 3) << 2;
    const int br = tid >> 4;
    const int bc = (tid & 15) << 2;
    float acc[4][4] = {};
    for (int k0 = 0; k0 < K; k0 += 16) {
        float4 av;
        if (bm + ar < M) av = *(const float4*)(A + (size_t)(bm + ar) * K + k0 + ac);
        else             av = make_float4(0.f, 0.f, 0.f, 0.f);
        const float4 bv = *(const float4*)(B + (size_t)(k0 + br) * N + bn + bc);
        As[ac + 0][ar] = av.x; As[ac + 1][ar] = av.y;
        As[ac + 2][ar] = av.z; As[ac + 3][ar] = av.w;
        *(float4*)&Bs[br][bc] = bv;
        __syncthreads();
#pragma unroll
        for (int kk = 0; kk < 16; ++kk) {
            const float4 a = *(const float4*)&As[kk][ty << 2];
            const float4 b = *(const float4*)&Bs[kk][tx << 2];
            acc[0][0] += a.x * b.x; acc[0][1] += a.x * b.y; acc[0][2] += a.x * b.z; acc[0][3] += a.x * b.w;
            acc[1][0] += a.y * b.x; acc[1][1] += a.y * b.y; acc[1][2] += a.y * b.z; acc[1][3] += a.y * b.w;
            acc[2][0] += a.z * b.x; acc[2][1] += a.z * b.y; acc[2][2] += a.z * b.z; acc[2][3] += a.z * b.w;
            acc[3][0] += a.w * b.x; acc[3][1] += a.w * b.y; acc[3][2] += a.w * b.z; acc[3][3] += a.w * b.w;
        }
        __syncthreads();
    }
#pragma unroll
    for (int i = 0; i < 4; ++i) {
        const int row = bm + (ty << 2) + i;
        if (row >= M) continue;
#pragma unroll
        for (int j = 0; j < 4; ++j) {
            const int col = bn + (tx << 2) + j;
            float val = acc[i][j] + bias[col];
            if (RELU) val = fmaxf(val, 0.f);
            C[(size_t)row * N + col] = val;
        }
    }
}

// ---------------- weight transpose+cast: src f32 [K][N] -> dst bf16 [N][K] --
__global__ __launch_bounds__(256) void transpose_cast(const float* __restrict__ S0,
        const float* __restrict__ S1, const float* __restrict__ S2,
        const float* __restrict__ S3, ushort_t* __restrict__ dst, int K, int N) {
    __shared__ float t[32][33];
    const float* src = (blockIdx.z == 0) ? S0 : (blockIdx.z == 1) ? S1 :
                       (blockIdx.z == 2) ? S2 : S3;
    ushort_t* d = dst + (size_t)blockIdx.z * K * N;
    const int n0 = blockIdx.x * 32, k0 = blockIdx.y * 32;
    const int tx = threadIdx.x & 31, ty = threadIdx.x >> 5;
#pragma unroll
    for (int i = 0; i < 4; ++i)
        t[ty + i * 8][tx] = src[(size_t)(k0 + ty + i * 8) * N + n0 + tx];
    __syncthreads();
#pragma unroll
    for (int i = 0; i < 4; ++i)
        d[(size_t)(n0 + ty + i * 8) * K + k0 + tx] = f2b(t[tx][ty + i * 8]);
}

// ---------------- bf16 MFMA GEMM: C = A[M,K] @ Bt[N,K]^T + bias -------------
// 128x64 tile, BK=32, 4 waves (2x2), per wave 4x2 frags of 16x16x32.
template<int RELU>
__global__ __launch_bounds__(256) void gemm_mfma(const ushort_t* __restrict__ A,
        const ushort_t* __restrict__ Bt, const float* __restrict__ bias,
        float* __restrict__ Cf, ushort_t* __restrict__ Cb, int M, int N, int K) {
    __shared__ ushort_t As[128][40];   // 32 k + 8 pad (80B stride)
    __shared__ ushort_t Bs[64][40];
    const int tid = threadIdx.x;
    const int lane = tid & 63, w = tid >> 6;
    const int l15 = lane & 15, lg = lane >> 4;
    const int bm = blockIdx.y * 128, bn = blockIdx.x * 64;
    const int wm = (w >> 1) * 64, wn = (w & 1) * 32;
    const int sr = tid >> 2, sc = (tid & 3) * 8;       // staging coords
    f32x4 acc[4][2];
#pragma unroll
    for (int mi = 0; mi < 4; ++mi)
#pragma unroll
        for (int ni = 0; ni < 2; ++ni)
            acc[mi][ni] = (f32x4){0.f, 0.f, 0.f, 0.f};

    for (int k0 = 0; k0 < K; k0 += 32) {
        const int ra0 = min(bm + sr, M - 1);
        const int ra1 = min(bm + 64 + sr, M - 1);
        const uint4 a0 = *(const uint4*)(A + (size_t)ra0 * K + k0 + sc);
        const uint4 a1 = *(const uint4*)(A + (size_t)ra1 * K + k0 + sc);
        const uint4 b0 = *(const uint4*)(Bt + (size_t)(bn + sr) * K + k0 + sc);
        __syncthreads();
        *(uint4*)&As[sr][sc] = a0;
        *(uint4*)&As[64 + sr][sc] = a1;
        *(uint4*)&Bs[sr][sc] = b0;
        __syncthreads();
        bf16x8 af[4], bfr[2];
#pragma unroll
        for (int mi = 0; mi < 4; ++mi)
            af[mi] = *(const bf16x8*)&As[wm + mi * 16 + l15][lg * 8];
#pragma unroll
        for (int ni = 0; ni < 2; ++ni)
            bfr[ni] = *(const bf16x8*)&Bs[wn + ni * 16 + l15][lg * 8];
#pragma unroll
        for (int mi = 0; mi < 4; ++mi)
#pragma unroll
            for (int ni = 0; ni < 2; ++ni)
                acc[mi][ni] = __builtin_amdgcn_mfma_f32_16x16x32_bf16(
                    af[mi], bfr[ni], acc[mi][ni], 0, 0, 0);
    }
#pragma unroll
    for (int mi = 0; mi < 4; ++mi)
#pragma unroll
        for (int ni = 0; ni < 2; ++ni)
#pragma unroll
            for (int r = 0; r < 4; ++r) {
                const int row = bm + wm + mi * 16 + lg * 4 + r;
                if (row >= M) continue;
                const int col = bn + wn + ni * 16 + l15;
                float v = acc[mi][ni][r] + bias[col];
                if (RELU) v = fmaxf(v, 0.f);
                if (Cf) Cf[(size_t)row * N + col] = v;
                if (Cb) Cb[(size_t)row * N + col] = f2b(v);
            }
}

// ---------------- flash MFMA attention --------------------------------------
// block = (64-query tile, head); 4 waves, wave w owns 16 queries.
__global__ __launch_bounds__(256) void attn_mfma(const ushort_t* __restrict__ Q,
        const ushort_t* __restrict__ K, const ushort_t* __restrict__ V,
        ushort_t* __restrict__ O) {
    __shared__ ushort_t Qs[64][104];     // 96 + 8 pad (208B stride)
    __shared__ ushort_t Ks[64][104];
    __shared__ ushort_t Vt[96][72];      // transposed V, XOR key-swizzle, 144B
    __shared__ ushort_t Ps[4][16][72];   // per-wave P tile
    const int q0 = blockIdx.x * 64;
    const int h = blockIdx.y;
    const int tid = threadIdx.x;
    const int lane = tid & 63, w = tid >> 6;
    const int l15 = lane & 15, lg = lane >> 4;
    const float scale = 0.10206207261596577f;   // 1/sqrt(96)

    // stage Q tile (reg->LDS, padded rows)
#pragma unroll
    for (int i = 0; i < 3; ++i) {
        const int ch = i * 256 + tid;
        const int r = ch / 12, c = (ch % 12) * 8;
        const uint4 v4 = *(const uint4*)(Q + (size_t)(q0 + r) * D + h * DKD + c);
        *(uint4*)&Qs[r][c] = v4;
    }
    float m_run[4], l_run[4];
    f32x4 acc_o[6];
#pragma unroll
    for (int r = 0; r < 4; ++r) { m_run[r] = -1e30f; l_run[r] = 0.f; }
#pragma unroll
    for (int nt = 0; nt < 6; ++nt) acc_o[nt] = (f32x4){0.f, 0.f, 0.f, 0.f};

    for (int s0 = 0; s0 < TT; s0 += 64) {
        __syncthreads();   // Q ready / prev tile consumed
#pragma unroll
        for (int i = 0; i < 3; ++i) {
            const int ch = i * 256 + tid;
            const int r = ch / 12, c = (ch % 12) * 8;
            const uint4 kv = *(const uint4*)(K + (size_t)(s0 + r) * D + h * DKD + c);
            *(uint4*)&Ks[r][c] = kv;
            const uint4 vv = *(const uint4*)(V + (size_t)(s0 + r) * D + h * DKD + c);
            const ushort_t* pv = (const ushort_t*)&vv;
            const int kk = r ^ (((c >> 3) & 7) << 3);   // key slot swizzle
#pragma unroll
            for (int j = 0; j < 8; ++j) Vt[c + j][kk] = pv[j];
        }
        __syncthreads();

        // S = Q K^T (this wave's 16 query rows x 64 keys)
        f32x4 accs[4];
#pragma unroll
        for (int ni = 0; ni < 4; ++ni) accs[ni] = (f32x4){0.f, 0.f, 0.f, 0.f};
#pragma unroll
        for (int ks = 0; ks < 3; ++ks) {
            const bf16x8 aq = *(const bf16x8*)&Qs[w * 16 + l15][ks * 32 + lg * 8];
#pragma unroll
            for (int ni = 0; ni < 4; ++ni) {
                const bf16x8 bk = *(const bf16x8*)&Ks[ni * 16 + l15][ks * 32 + lg * 8];
                accs[ni] = __builtin_amdgcn_mfma_f32_16x16x32_bf16(aq, bk, accs[ni], 0, 0, 0);
            }
        }
        // online softmax (rows = lg*4 + r, owned by the 16-lane group)
        float ps[4][4];
#pragma unroll
        for (int r = 0; r < 4; ++r) {
#pragma unroll
            for (int ni = 0; ni < 4; ++ni) ps[ni][r] = accs[ni][r] * scale;
            float mx = fmaxf(fmaxf(ps[0][r], ps[1][r]), fmaxf(ps[2][r], ps[3][r]));
#pragma unroll
            for (int o = 1; o <= 8; o <<= 1) mx = fmaxf(mx, __shfl_xor(mx, o));
            const float mnew = fmaxf(m_run[r], mx);
            const float sf = __expf(m_run[r] - mnew);
            m_run[r] = mnew;
            float rs = 0.f;
#pragma unroll
            for (int ni = 0; ni < 4; ++ni) {
                ps[ni][r] = __expf(ps[ni][r] - mnew);
                rs += ps[ni][r];
            }
#pragma unroll
            for (int o = 1; o <= 8; o <<= 1) rs += __shfl_xor(rs, o);
            l_run[r] = l_run[r] * sf + rs;
#pragma unroll
            for (int nt = 0; nt < 6; ++nt) acc_o[nt][r] *= sf;
        }
        // P -> per-wave LDS (bf16), re-layout for PV A-operand
#pragma unroll
        for (int ni = 0; ni < 4; ++ni)
#pragma unroll
            for (int r = 0; r < 4; ++r)
                Ps[w][lg * 4 + r][ni * 16 + l15] = f2b(ps[ni][r]);
        // O += P @ V
#pragma unroll
        for (int ks = 0; ks < 2; ++ks) {
            const bf16x8 ap = *(const bf16x8*)&Ps[w][l15][ks * 32 + lg * 8];
#pragma unroll
            for (int nt = 0; nt < 6; ++nt) {
                const int dim = nt * 16 + l15;
                const int kcol = (ks * 32 + lg * 8) ^ (((dim >> 3) & 7) << 3);
                const bf16x8 bv = *(const bf16x8*)&Vt[dim][kcol];
                acc_o[nt] = __builtin_amdgcn_mfma_f32_16x16x32_bf16(ap, bv, acc_o[nt], 0, 0, 0);
            }
        }
    }
    // epilogue: O /= l, write bf16
#pragma unroll
    for (int nt = 0; nt < 6; ++nt)
#pragma unroll
        for (int r = 0; r < 4; ++r) {
            const int row = q0 + w * 16 + lg * 4 + r;
            const int col = h * DKD + nt * 16 + l15;
            O[(size_t)row * D + col] = f2b(acc_o[nt][r] / l_run[r]);
        }
}

// ---------------- x = LN(x + y); writes fp32 x and bf16 xb ------------------
__global__ __launch_bounds__(256) void add_ln(float* __restrict__ x,
        const float* __restrict__ y, const float* __restrict__ g,
        const float* __restrict__ b, ushort_t* __restrict__ xb) {
    __shared__ float red[4];
    const int row = blockIdx.x;
    const int tid = threadIdx.x;
    float vals[3];
    float s = 0.f;
#pragma unroll
    for (int i = 0; i < 3; ++i) {
        const int c = tid + i * 256;
        const float t = x[(size_t)row * D + c] + y[(size_t)row * D + c];
        vals[i] = t; s += t;
    }
    const float mean = block_sum(s, red) * (1.f / 768.f);
    float s2 = 0.f;
#pragma unroll
    for (int i = 0; i < 3; ++i) { const float dd = vals[i] - mean; s2 += dd * dd; }
    const float var = block_sum(s2, red) * (1.f / 768.f);
    const float inv = rsqrtf(var + 1e-5f);
#pragma unroll
    for (int i = 0; i < 3; ++i) {
        const int c = tid + i * 256;
        const float o = (vals[i] - mean) * inv * g[c] + b[c];
        x[(size_t)row * D + c] = o;
        xb[(size_t)row * D + c] = f2b(o);
    }
}

// ---------------- predictor -------------------------------------------------
__global__ __launch_bounds__(256) void predict_k(const float* __restrict__ x,
        const float* __restrict__ pw, const float* __restrict__ pb,
        float* __restrict__ out) {
    __shared__ float red[4];
    const int r = blockIdx.x;
    const int tid = threadIdx.x;
    float best = -1e30f;
    for (int bag = 0; bag < BAG; ++bag) {
        const int row = (bag * SPANS) * E + (bag * SPANS + 1);
        const float* f = x + (size_t)row * D;
        float acc = 0.f;
        for (int d = tid; d < D; d += 256) acc += f[d] * pw[(size_t)d * NREL + r];
        best = fmaxf(best, block_sum(acc, red));
    }
    if (tid == 0) out[r] = best + pb[r];
}

extern "C" void kernel_launch(void* const* d_in, const int* in_sizes, int n_in,
                              void* d_out, int out_size, void* d_ws, size_t ws_size,
                              hipStream_t stream) {
    const float* emb  = (const float*)d_in[0];
    const int*  spans = (const int*)d_in[1];
    const float* wu_w = (const float*)d_in[2];  const float* wu_b = (const float*)d_in[3];
    const float* wvv_w= (const float*)d_in[4];  const float* wvv_b= (const float*)d_in[5];
    const float* lnr_w= (const float*)d_in[6];  const float* lnr_b= (const float*)d_in[7];
    const float* wq = (const float*)d_in[8];    const float* bq = (const float*)d_in[9];
    const float* wk = (const float*)d_in[10];   const float* bk = (const float*)d_in[11];
    const float* wv = (const float*)d_in[12];   const float* bv = (const float*)d_in[13];
    const float* wo = (const float*)d_in[14];   const float* bo = (const float*)d_in[15];
    const float* w1 = (const float*)d_in[16];   const float* b1 = (const float*)d_in[17];
    const float* w2 = (const float*)d_in[18];   const float* b2 = (const float*)d_in[19];
    const float* g1 = (const float*)d_in[20];   const float* be1= (const float*)d_in[21];
    const float* g2 = (const float*)d_in[22];   const float* be2= (const float*)d_in[23];
    const float* pw = (const float*)d_in[24];   const float* pb = (const float*)d_in[25];

    // workspace layout (~34.8 MB)
    char* cur = (char*)d_ws;
    auto alloc = [&](size_t bytes) { char* p = cur; cur += (bytes + 255) & ~(size_t)255; return p; };
    float*    htb  = (float*)alloc(E * D * 4);
    float*    ub   = (float*)alloc(E * D * 4);
    float*    vb   = (float*)alloc(E * D * 4);
    float*    x    = (float*)alloc((size_t)TT * D * 4);
    float*    tb   = (float*)alloc((size_t)TT * D * 4);
    ushort_t* xb   = (ushort_t*)alloc((size_t)TT * D * 2);
    ushort_t* qb   = (ushort_t*)alloc((size_t)TT * D * 2);
    ushort_t* kb   = (ushort_t*)alloc((size_t)TT * D * 2);
    ushort_t* vvb  = (ushort_t*)alloc((size_t)TT * D * 2);
    ushort_t* ob   = (ushort_t*)alloc((size_t)TT * D * 2);   // alpha, then attn out
    ushort_t* fb   = (ushort_t*)alloc((size_t)TT * FFD * 2);
    ushort_t* lnrT = (ushort_t*)alloc((size_t)D * D * 2);
    ushort_t* wT4  = (ushort_t*)alloc((size_t)4 * D * D * 2);
    ushort_t* w1T  = (ushort_t*)alloc((size_t)D * FFD * 2);
    ushort_t* w2T  = (ushort_t*)alloc((size_t)FFD * D * 2);

    const int DD = D * D;
    const dim3 gT(TT / 64, (TT + 127) / 128);   // (12 cols for N=768) set per call

    span_pool<<<E, 256, 0, stream>>>(emb, spans, htb);
    gemm_f32<0><<<dim3(D / 64, 1), 256, 0, stream>>>(htb, wu_w, wu_b, ub, E, D, D);
    gemm_f32<0><<<dim3(D / 64, 1), 256, 0, stream>>>(htb, wvv_w, wvv_b, vb, E, D, D);
    alpha_k<<<TT, 256, 0, stream>>>(ub, vb, ob);
    transpose_cast<<<dim3(D / 32, D / 32, 1), 256, 0, stream>>>(lnr_w, lnr_w, lnr_w, lnr_w, lnrT, D, D);
    gemm_mfma<1><<<dim3(D / 64, (TT + 127) / 128), 256, 0, stream>>>(ob, lnrT, lnr_b, x, xb, TT, D, D);

    for (int l = 0; l < LAY; ++l) {
        transpose_cast<<<dim3(D / 32, D / 32, 4), 256, 0, stream>>>(
            wq + (size_t)l * DD, wk + (size_t)l * DD, wv + (size_t)l * DD, wo + (size_t)l * DD, wT4, D, D);
        transpose_cast<<<dim3(FFD / 32, D / 32, 1), 256, 0, stream>>>(
            w1 + (size_t)l * D * FFD, w1, w1, w1, w1T, D, FFD);
        transpose_cast<<<dim3(D / 32, FFD / 32, 1), 256, 0, stream>>>(
            w2 + (size_t)l * FFD * D, w2, w2, w2, w2T, FFD, D);

        gemm_mfma<0><<<dim3(D / 64, (TT + 127) / 128), 256, 0, stream>>>(xb, wT4 + 0 * DD, bq + l * D, nullptr, qb, TT, D, D);
        gemm_mfma<0><<<dim3(D / 64, (TT + 127) / 128), 256, 0, stream>>>(xb, wT4 + 1 * DD, bk + l * D, nullptr, kb, TT, D, D);
        gemm_mfma<0><<<dim3(D / 64, (TT + 127) / 128), 256, 0, stream>>>(xb, wT4 + 2 * DD, bv + l * D, nullptr, vvb, TT, D, D);
        attn_mfma<<<dim3(TT / 64, H), 256, 0, stream>>>(qb, kb, vvb, ob);
        gemm_mfma<0><<<dim3(D / 64, (TT + 127) / 128), 256, 0, stream>>>(ob, wT4 + 3 * DD, bo + l * D, tb, nullptr, TT, D, D);
        add_ln<<<TT, 256, 0, stream>>>(x, tb, g1 + l * D, be1 + l * D, xb);
        gemm_mfma<1><<<dim3(FFD / 64, (TT + 127) / 128), 256, 0, stream>>>(xb, w1T, b1 + l * FFD, nullptr, fb, TT, FFD, D);
        gemm_mfma<0><<<dim3(D / 64, (TT + 127) / 128), 256, 0, stream>>>(fb, w2T, b2 + l * D, tb, nullptr, TT, D, FFD);
        add_ln<<<TT, 256, 0, stream>>>(x, tb, g2 + l * D, be2 + l * D, xb);
    }

    predict_k<<<NREL, 256, 0, stream>>>(x, pw, pb, (float*)d_out);
    (void)in_sizes; (void)n_in; (void)out_size; (void)ws_size; (void)gT;
}

// Round 3
// 912.066 us; speedup vs baseline: 6.8671x; 1.4378x over previous
//
#include <hip/hip_runtime.h>

// Codred forward. R2:
//  - span_pool parallelized over positions (two-phase max) — was 240us @ 0.9% occ
//  - QKV projections fused into one GEMM (N=2304), bias concat once
//  - gemm_mfma staging via __builtin_amdgcn_global_load_lds width=16 (m97 pattern),
//    linear LDS tiles, per-lane global row clamp for the M=1600 tail tile
//  - attn: flash-style MFMA (unchanged math), now reads fused qkv buffer (ld=2304)

#define D    768
#define H    8
#define DKD  96
#define LAY  4
#define FFD  1024
#define NREL 97
#define BAG  8
#define SPANS 5
#define E    40
#define TT   1600
#define SEQ  512
#define D3   2304   // fused qkv width

typedef __attribute__((ext_vector_type(8))) short bf16x8;
typedef __attribute__((ext_vector_type(4))) float f32x4;
typedef unsigned short ushort_t;
typedef unsigned int uint_t;

__device__ __forceinline__ ushort_t f2b(float x) {
    uint_t u = __builtin_bit_cast(uint_t, x);
    return (ushort_t)((u + 0x7fffu + ((u >> 16) & 1u)) >> 16);   // RNE
}

__device__ __forceinline__ void gload16(const void* g, void* l) {
    __builtin_amdgcn_global_load_lds(
        (const __attribute__((address_space(1))) unsigned int*)g,
        (__attribute__((address_space(3))) unsigned int*)l, 16, 0, 0);
}

// ---------------- block reductions (256 thr) --------------------------------
__device__ __forceinline__ float block_sum(float v, float* red) {
#pragma unroll
    for (int o = 32; o >= 1; o >>= 1) v += __shfl_xor(v, o);
    __syncthreads();
    if ((threadIdx.x & 63) == 0) red[threadIdx.x >> 6] = v;
    __syncthreads();
    return red[0] + red[1] + red[2] + red[3];
}

// ---------------- span max-pool, phase 1: per 64-position group -------------
__global__ __launch_bounds__(256) void span_pool_p1(const float* __restrict__ emb,
        const int* __restrict__ spans, float* __restrict__ partial) {
    const int e = blockIdx.x, pg = blockIdx.y;
    const int bag = e / SPANS;
    const int st = spans[e * 2 + 0];
    const int en = spans[e * 2 + 1];
    const int p0 = max(st, pg * 64);
    const int p1 = min(en, pg * 64 + 63);
    const int tid = threadIdx.x;
    if (tid >= 192) return;
    float4 m = make_float4(-1e30f, -1e30f, -1e30f, -1e30f);
    for (int p = p0; p <= p1; ++p) {
        const float4 v = *(const float4*)(emb + ((size_t)bag * SEQ + p) * D + tid * 4);
        m.x = fmaxf(m.x, v.x); m.y = fmaxf(m.y, v.y);
        m.z = fmaxf(m.z, v.z); m.w = fmaxf(m.w, v.w);
    }
    *(float4*)(partial + ((size_t)e * 8 + pg) * D + tid * 4) = m;
}

// ---------------- span max-pool, phase 2: reduce 8 partials ------------------
__global__ __launch_bounds__(256) void span_pool_p2(const float* __restrict__ partial,
        float* __restrict__ htb) {
    const int e = blockIdx.x;
    const int tid = threadIdx.x;
    if (tid >= 192) return;
    float4 m = make_float4(-1e30f, -1e30f, -1e30f, -1e30f);
#pragma unroll
    for (int pg = 0; pg < 8; ++pg) {
        const float4 v = *(const float4*)(partial + ((size_t)e * 8 + pg) * D + tid * 4);
        m.x = fmaxf(m.x, v.x); m.y = fmaxf(m.y, v.y);
        m.z = fmaxf(m.z, v.z); m.w = fmaxf(m.w, v.w);
    }
    *(float4*)(htb + (size_t)e * D + tid * 4) = m;
}

// ---------------- alpha (bf16 out) ------------------------------------------
__global__ __launch_bounds__(256) void alpha_k(const float* __restrict__ u,
        const float* __restrict__ v, ushort_t* __restrict__ a) {
    const int ij = blockIdx.x;
    const int i = ij / E, j = ij % E;
    const int tid = threadIdx.x;
#pragma unroll
    for (int t2 = 0; t2 < 3; ++t2) {
        const int d = tid + t2 * 256;
        a[(size_t)ij * D + d] = f2b(fmaxf(u[(size_t)i * D + d] + v[(size_t)j * D + d], 0.f));
    }
}

// ---------------- fp32 GEMM for u,v (M=40), fused via blockIdx.z ------------
__global__ __launch_bounds__(256) void gemm_uv(const float* __restrict__ A,
        const float* __restrict__ B0, const float* __restrict__ bias0, float* __restrict__ C0,
        const float* __restrict__ B1, const float* __restrict__ bias1, float* __restrict__ C1,
        int M, int N, int K) {
    const float* B = blockIdx.z ? B1 : B0;
    const float* bias = blockIdx.z ? bias1 : bias0;
    float* C = blockIdx.z ? C1 : C0;
    __shared__ float As[16][68];
    __shared__ float Bs[16][68];
    const int bn = blockIdx.x * 64;
    const int bm = blockIdx.y * 64;
    const int tid = threadIdx.x;
    const int tx = tid & 15;
    const int ty = tid >> 4;
    const int ar = tid >> 2;
    const int ac = (tid & 3) << 2;
    const int br = tid >> 4;
    const int bc = (tid & 15) << 2;
    float acc[4][4] = {};
    for (int k0 = 0; k0 < K; k0 += 16) {
        float4 av;
        if (bm + ar < M) av = *(const float4*)(A + (size_t)(bm + ar) * K + k0 + ac);
        else             av = make_float4(0.f, 0.f, 0.f, 0.f);
        const float4 bv = *(const float4*)(B + (size_t)(k0 + br) * N + bn + bc);
        As[ac + 0][ar] = av.x; As[ac + 1][ar] = av.y;
        As[ac + 2][ar] = av.z; As[ac + 3][ar] = av.w;
        *(float4*)&Bs[br][bc] = bv;
        __syncthreads();
#pragma unroll
        for (int kk = 0; kk < 16; ++kk) {
            const float4 a = *(const float4*)&As[kk][ty << 2];
            const float4 b = *(const float4*)&Bs[kk][tx << 2];
            acc[0][0] += a.x * b.x; acc[0][1] += a.x * b.y; acc[0][2] += a.x * b.z; acc[0][3] += a.x * b.w;
            acc[1][0] += a.y * b.x; acc[1][1] += a.y * b.y; acc[1][2] += a.y * b.z; acc[1][3] += a.y * b.w;
            acc[2][0] += a.z * b.x; acc[2][1] += a.z * b.y; acc[2][2] += a.z * b.z; acc[2][3] += a.z * b.w;
            acc[3][0] += a.w * b.x; acc[3][1] += a.w * b.y; acc[3][2] += a.w * b.z; acc[3][3] += a.w * b.w;
        }
        __syncthreads();
    }
#pragma unroll
    for (int i = 0; i < 4; ++i) {
        const int row = bm + (ty << 2) + i;
        if (row >= M) continue;
#pragma unroll
        for (int j = 0; j < 4; ++j) {
            const int col = bn + (tx << 2) + j;
            C[(size_t)row * N + col] = acc[i][j] + bias[col];
        }
    }
}

// ---------------- weight transpose+cast: src f32 [K][N] -> dst bf16 [N][K] --
__global__ __launch_bounds__(256) void transpose_cast(const float* __restrict__ S0,
        const float* __restrict__ S1, const float* __restrict__ S2,
        const float* __restrict__ S3, ushort_t* __restrict__ dst, int K, int N) {
    __shared__ float t[32][33];
    const float* src = (blockIdx.z == 0) ? S0 : (blockIdx.z == 1) ? S1 :
                       (blockIdx.z == 2) ? S2 : S3;
    ushort_t* d = dst + (size_t)blockIdx.z * K * N;
    const int n0 = blockIdx.x * 32, k0 = blockIdx.y * 32;
    const int tx = threadIdx.x & 31, ty = threadIdx.x >> 5;
#pragma unroll
    for (int i = 0; i < 4; ++i)
        t[ty + i * 8][tx] = src[(size_t)(k0 + ty + i * 8) * N + n0 + tx];
    __syncthreads();
#pragma unroll
    for (int i = 0; i < 4; ++i)
        d[(size_t)(n0 + ty + i * 8) * K + k0 + tx] = f2b(t[tx][ty + i * 8]);
}

// ---------------- concat qkv bias: [L][2304] ---------------------------------
__global__ __launch_bounds__(256) void concat_bias(const float* __restrict__ bq,
        const float* __restrict__ bk, const float* __restrict__ bv,
        float* __restrict__ dst) {
    const int i = blockIdx.x * 256 + threadIdx.x;
    if (i >= LAY * D3) return;
    const int l = i / D3, j = i % D3;
    float v;
    if (j < D) v = bq[l * D + j];
    else if (j < 2 * D) v = bk[l * D + j - D];
    else v = bv[l * D + j - 2 * D];
    dst[i] = v;
}

// ---------------- bf16 MFMA GEMM: C = A[M,K] @ Bt[N,K]^T + bias -------------
// 128x64 tile, BK=32, 4 waves (2x2). Staging via global_load_lds width=16
// into LINEAR LDS tiles (wave-uniform dest + lane*16; per-lane global addr).
template<int RELU>
__global__ __launch_bounds__(256) void gemm_mfma(const ushort_t* __restrict__ A,
        const ushort_t* __restrict__ Bt, const float* __restrict__ bias,
        float* __restrict__ Cf, ushort_t* __restrict__ Cb, int M, int N, int K) {
    __shared__ ushort_t As[128 * 32];   // linear: row*32 + col
    __shared__ ushort_t Bs[64 * 32];
    const int tid = threadIdx.x;
    const int lane = tid & 63, w = tid >> 6;
    const int l15 = lane & 15, lg = lane >> 4;
    const int bm = blockIdx.y * 128, bn = blockIdx.x * 64;
    const int wm = (w >> 1) * 64, wn = (w & 1) * 32;
    // staging coords: each wave loads 2x16 rows of A, 1x16 rows of B
    const int trA0 = w * 32 + (lane >> 2);          // tile row, A instr 0
    const int trA1 = trA0 + 16;                     // A instr 1
    const int trB  = w * 16 + (lane >> 2);          // tile row, B
    const int sc   = (lane & 3) * 8;                // bf16 col within BK=32
    const size_t rowA0 = (size_t)min(bm + trA0, M - 1) * K;
    const size_t rowA1 = (size_t)min(bm + trA1, M - 1) * K;
    const size_t rowB  = (size_t)(bn + trB) * K;
    ushort_t* asd0 = As + w * 1024;                 // w*32 rows * 32 cols
    ushort_t* asd1 = As + w * 1024 + 512;
    ushort_t* bsd  = Bs + w * 512;

    f32x4 acc[4][2];
#pragma unroll
    for (int mi = 0; mi < 4; ++mi)
#pragma unroll
        for (int ni = 0; ni < 2; ++ni)
            acc[mi][ni] = (f32x4){0.f, 0.f, 0.f, 0.f};

    for (int k0 = 0; k0 < K; k0 += 32) {
        __syncthreads();                            // prev reads complete
        gload16(A + rowA0 + k0 + sc, asd0);
        gload16(A + rowA1 + k0 + sc, asd1);
        gload16(Bt + rowB + k0 + sc, bsd);
        __syncthreads();                            // staging complete (vmcnt drained)
        bf16x8 af[4], bfr[2];
#pragma unroll
        for (int mi = 0; mi < 4; ++mi)
            af[mi] = *(const bf16x8*)&As[(wm + mi * 16 + l15) * 32 + lg * 8];
#pragma unroll
        for (int ni = 0; ni < 2; ++ni)
            bfr[ni] = *(const bf16x8*)&Bs[(wn + ni * 16 + l15) * 32 + lg * 8];
#pragma unroll
        for (int mi = 0; mi < 4; ++mi)
#pragma unroll
            for (int ni = 0; ni < 2; ++ni)
                acc[mi][ni] = __builtin_amdgcn_mfma_f32_16x16x32_bf16(
                    af[mi], bfr[ni], acc[mi][ni], 0, 0, 0);
    }
#pragma unroll
    for (int mi = 0; mi < 4; ++mi)
#pragma unroll
        for (int ni = 0; ni < 2; ++ni)
#pragma unroll
            for (int r = 0; r < 4; ++r) {
                const int row = bm + wm + mi * 16 + lg * 4 + r;
                if (row >= M) continue;
                const int col = bn + wn + ni * 16 + l15;
                float v = acc[mi][ni][r] + bias[col];
                if (RELU) v = fmaxf(v, 0.f);
                if (Cf) Cf[(size_t)row * N + col] = v;
                if (Cb) Cb[(size_t)row * N + col] = f2b(v);
            }
}

// ---------------- flash MFMA attention --------------------------------------
// block = (64-query tile, head); 4 waves, wave w owns 16 queries.
// Q,K,V read from the fused qkv buffer with row stride ldin (=2304).
__global__ __launch_bounds__(256) void attn_mfma(const ushort_t* __restrict__ Q,
        const ushort_t* __restrict__ K, const ushort_t* __restrict__ V,
        ushort_t* __restrict__ O, int ldin) {
    __shared__ ushort_t Qs[64][104];     // 96 + 8 pad (208B stride)
    __shared__ ushort_t Ks[64][104];
    __shared__ ushort_t Vt[96][72];      // transposed V, XOR key-swizzle
    __shared__ ushort_t Ps[4][16][72];   // per-wave P tile
    const int q0 = blockIdx.x * 64;
    const int h = blockIdx.y;
    const int tid = threadIdx.x;
    const int lane = tid & 63, w = tid >> 6;
    const int l15 = lane & 15, lg = lane >> 4;
    const float scale = 0.10206207261596577f;   // 1/sqrt(96)

#pragma unroll
    for (int i = 0; i < 3; ++i) {
        const int ch = i * 256 + tid;
        const int r = ch / 12, c = (ch % 12) * 8;
        const uint4 v4 = *(const uint4*)(Q + (size_t)(q0 + r) * ldin + h * DKD + c);
        *(uint4*)&Qs[r][c] = v4;
    }
    float m_run[4], l_run[4];
    f32x4 acc_o[6];
#pragma unroll
    for (int r = 0; r < 4; ++r) { m_run[r] = -1e30f; l_run[r] = 0.f; }
#pragma unroll
    for (int nt = 0; nt < 6; ++nt) acc_o[nt] = (f32x4){0.f, 0.f, 0.f, 0.f};

    for (int s0 = 0; s0 < TT; s0 += 64) {
        __syncthreads();
#pragma unroll
        for (int i = 0; i < 3; ++i) {
            const int ch = i * 256 + tid;
            const int r = ch / 12, c = (ch % 12) * 8;
            const uint4 kv = *(const uint4*)(K + (size_t)(s0 + r) * ldin + h * DKD + c);
            *(uint4*)&Ks[r][c] = kv;
            const uint4 vv = *(const uint4*)(V + (size_t)(s0 + r) * ldin + h * DKD + c);
            const ushort_t* pv = (const ushort_t*)&vv;
            const int kk = r ^ (((c >> 3) & 7) << 3);
#pragma unroll
            for (int j = 0; j < 8; ++j) Vt[c + j][kk] = pv[j];
        }
        __syncthreads();

        f32x4 accs[4];
#pragma unroll
        for (int ni = 0; ni < 4; ++ni) accs[ni] = (f32x4){0.f, 0.f, 0.f, 0.f};
#pragma unroll
        for (int ks = 0; ks < 3; ++ks) {
            const bf16x8 aq = *(const bf16x8*)&Qs[w * 16 + l15][ks * 32 + lg * 8];
#pragma unroll
            for (int ni = 0; ni < 4; ++ni) {
                const bf16x8 bk = *(const bf16x8*)&Ks[ni * 16 + l15][ks * 32 + lg * 8];
                accs[ni] = __builtin_amdgcn_mfma_f32_16x16x32_bf16(aq, bk, accs[ni], 0, 0, 0);
            }
        }
        float ps[4][4];
#pragma unroll
        for (int r = 0; r < 4; ++r) {
#pragma unroll
            for (int ni = 0; ni < 4; ++ni) ps[ni][r] = accs[ni][r] * scale;
            float mx = fmaxf(fmaxf(ps[0][r], ps[1][r]), fmaxf(ps[2][r], ps[3][r]));
#pragma unroll
            for (int o = 1; o <= 8; o <<= 1) mx = fmaxf(mx, __shfl_xor(mx, o));
            const float mnew = fmaxf(m_run[r], mx);
            const float sf = __expf(m_run[r] - mnew);
            m_run[r] = mnew;
            float rs = 0.f;
#pragma unroll
            for (int ni = 0; ni < 4; ++ni) {
                ps[ni][r] = __expf(ps[ni][r] - mnew);
                rs += ps[ni][r];
            }
#pragma unroll
            for (int o = 1; o <= 8; o <<= 1) rs += __shfl_xor(rs, o);
            l_run[r] = l_run[r] * sf + rs;
#pragma unroll
            for (int nt = 0; nt < 6; ++nt) acc_o[nt][r] *= sf;
        }
#pragma unroll
        for (int ni = 0; ni < 4; ++ni)
#pragma unroll
            for (int r = 0; r < 4; ++r)
                Ps[w][lg * 4 + r][ni * 16 + l15] = f2b(ps[ni][r]);
#pragma unroll
        for (int ks = 0; ks < 2; ++ks) {
            const bf16x8 ap = *(const bf16x8*)&Ps[w][l15][ks * 32 + lg * 8];
#pragma unroll
            for (int nt = 0; nt < 6; ++nt) {
                const int dim = nt * 16 + l15;
                const int kcol = (ks * 32 + lg * 8) ^ (((dim >> 3) & 7) << 3);
                const bf16x8 bv = *(const bf16x8*)&Vt[dim][kcol];
                acc_o[nt] = __builtin_amdgcn_mfma_f32_16x16x32_bf16(ap, bv, acc_o[nt], 0, 0, 0);
            }
        }
    }
#pragma unroll
    for (int nt = 0; nt < 6; ++nt)
#pragma unroll
        for (int r = 0; r < 4; ++r) {
            const int row = q0 + w * 16 + lg * 4 + r;
            const int col = h * DKD + nt * 16 + l15;
            O[(size_t)row * D + col] = f2b(acc_o[nt][r] / l_run[r]);
        }
}

// ---------------- x = LN(x + y); writes fp32 x and bf16 xb ------------------
__global__ __launch_bounds__(256) void add_ln(float* __restrict__ x,
        const float* __restrict__ y, const float* __restrict__ g,
        const float* __restrict__ b, ushort_t* __restrict__ xb) {
    __shared__ float red[4];
    const int row = blockIdx.x;
    const int tid = threadIdx.x;
    float vals[3];
    float s = 0.f;
#pragma unroll
    for (int i = 0; i < 3; ++i) {
        const int c = tid + i * 256;
        const float t = x[(size_t)row * D + c] + y[(size_t)row * D + c];
        vals[i] = t; s += t;
    }
    const float mean = block_sum(s, red) * (1.f / 768.f);
    float s2 = 0.f;
#pragma unroll
    for (int i = 0; i < 3; ++i) { const float dd = vals[i] - mean; s2 += dd * dd; }
    const float var = block_sum(s2, red) * (1.f / 768.f);
    const float inv = rsqrtf(var + 1e-5f);
#pragma unroll
    for (int i = 0; i < 3; ++i) {
        const int c = tid + i * 256;
        const float o = (vals[i] - mean) * inv * g[c] + b[c];
        x[(size_t)row * D + c] = o;
        xb[(size_t)row * D + c] = f2b(o);
    }
}

// ---------------- predictor -------------------------------------------------
__global__ __launch_bounds__(256) void predict_k(const float* __restrict__ x,
        const float* __restrict__ pw, const float* __restrict__ pb,
        float* __restrict__ out) {
    __shared__ float red[4];
    const int r = blockIdx.x;
    const int tid = threadIdx.x;
    float best = -1e30f;
    for (int bag = 0; bag < BAG; ++bag) {
        const int row = (bag * SPANS) * E + (bag * SPANS + 1);
        const float* f = x + (size_t)row * D;
        float acc = 0.f;
        for (int d = tid; d < D; d += 256) acc += f[d] * pw[(size_t)d * NREL + r];
        best = fmaxf(best, block_sum(acc, red));
    }
    if (tid == 0) out[r] = best + pb[r];
}

extern "C" void kernel_launch(void* const* d_in, const int* in_sizes, int n_in,
                              void* d_out, int out_size, void* d_ws, size_t ws_size,
                              hipStream_t stream) {
    const float* emb  = (const float*)d_in[0];
    const int*  spans = (const int*)d_in[1];
    const float* wu_w = (const float*)d_in[2];  const float* wu_b = (const float*)d_in[3];
    const float* wvv_w= (const float*)d_in[4];  const float* wvv_b= (const float*)d_in[5];
    const float* lnr_w= (const float*)d_in[6];  const float* lnr_b= (const float*)d_in[7];
    const float* wq = (const float*)d_in[8];    const float* bq = (const float*)d_in[9];
    const float* wk = (const float*)d_in[10];   const float* bk = (const float*)d_in[11];
    const float* wv = (const float*)d_in[12];   const float* bv = (const float*)d_in[13];
    const float* wo = (const float*)d_in[14];   const float* bo = (const float*)d_in[15];
    const float* w1 = (const float*)d_in[16];   const float* b1 = (const float*)d_in[17];
    const float* w2 = (const float*)d_in[18];   const float* b2 = (const float*)d_in[19];
    const float* g1 = (const float*)d_in[20];   const float* be1= (const float*)d_in[21];
    const float* g2 = (const float*)d_in[22];   const float* be2= (const float*)d_in[23];
    const float* pw = (const float*)d_in[24];   const float* pb = (const float*)d_in[25];

    // workspace layout (~36 MB)
    char* cur = (char*)d_ws;
    auto alloc = [&](size_t bytes) { char* p = cur; cur += (bytes + 255) & ~(size_t)255; return p; };
    float*    htb  = (float*)alloc(E * D * 4);
    float*    ub   = (float*)alloc(E * D * 4);
    float*    vb   = (float*)alloc(E * D * 4);
    float*    part = (float*)alloc((size_t)E * 8 * D * 4);
    float*    x    = (float*)alloc((size_t)TT * D * 4);
    float*    tb   = (float*)alloc((size_t)TT * D * 4);
    ushort_t* xb   = (ushort_t*)alloc((size_t)TT * D * 2);
    ushort_t* qkv  = (ushort_t*)alloc((size_t)TT * D3 * 2);
    ushort_t* ob   = (ushort_t*)alloc((size_t)TT * D * 2);   // alpha, then attn out
    ushort_t* fb   = (ushort_t*)alloc((size_t)TT * FFD * 2);
    ushort_t* lnrT = (ushort_t*)alloc((size_t)D * D * 2);
    ushort_t* wT4  = (ushort_t*)alloc((size_t)4 * D * D * 2);  // qT,kT,vT contiguous = [2304][768]
    ushort_t* w1T  = (ushort_t*)alloc((size_t)D * FFD * 2);
    ushort_t* w2T  = (ushort_t*)alloc((size_t)FFD * D * 2);
    float*    bqkv = (float*)alloc((size_t)LAY * D3 * 4);

    const int DD = D * D;

    span_pool_p1<<<dim3(E, 8), 256, 0, stream>>>(emb, spans, part);
    span_pool_p2<<<E, 256, 0, stream>>>(part, htb);
    gemm_uv<<<dim3(D / 64, 1, 2), 256, 0, stream>>>(htb, wu_w, wu_b, ub, wvv_w, wvv_b, vb, E, D, D);
    alpha_k<<<TT, 256, 0, stream>>>(ub, vb, ob);
    transpose_cast<<<dim3(D / 32, D / 32, 1), 256, 0, stream>>>(lnr_w, lnr_w, lnr_w, lnr_w, lnrT, D, D);
    concat_bias<<<(LAY * D3 + 255) / 256, 256, 0, stream>>>(bq, bk, bv, bqkv);
    gemm_mfma<1><<<dim3(D / 64, (TT + 127) / 128), 256, 0, stream>>>(ob, lnrT, lnr_b, x, xb, TT, D, D);

    for (int l = 0; l < LAY; ++l) {
        transpose_cast<<<dim3(D / 32, D / 32, 4), 256, 0, stream>>>(
            wq + (size_t)l * DD, wk + (size_t)l * DD, wv + (size_t)l * DD, wo + (size_t)l * DD, wT4, D, D);
        transpose_cast<<<dim3(FFD / 32, D / 32, 1), 256, 0, stream>>>(
            w1 + (size_t)l * D * FFD, w1, w1, w1, w1T, D, FFD);
        transpose_cast<<<dim3(D / 32, FFD / 32, 1), 256, 0, stream>>>(
            w2 + (size_t)l * FFD * D, w2, w2, w2, w2T, FFD, D);

        // fused QKV projection: [1600,768] @ [2304,768]^T
        gemm_mfma<0><<<dim3(D3 / 64, (TT + 127) / 128), 256, 0, stream>>>(
            xb, wT4, bqkv + l * D3, nullptr, qkv, TT, D3, D);
        attn_mfma<<<dim3(TT / 64, H), 256, 0, stream>>>(
            qkv, qkv + D, qkv + 2 * D, ob, D3);
        gemm_mfma<0><<<dim3(D / 64, (TT + 127) / 128), 256, 0, stream>>>(
            ob, wT4 + 3 * DD, bo + l * D, tb, nullptr, TT, D, D);
        add_ln<<<TT, 256, 0, stream>>>(x, tb, g1 + l * D, be1 + l * D, xb);
        gemm_mfma<1><<<dim3(FFD / 64, (TT + 127) / 128), 256, 0, stream>>>(
            xb, w1T, b1 + l * FFD, nullptr, fb, TT, FFD, D);
        gemm_mfma<0><<<dim3(D / 64, (TT + 127) / 128), 256, 0, stream>>>(
            fb, w2T, b2 + l * D, tb, nullptr, TT, D, FFD);
        add_ln<<<TT, 256, 0, stream>>>(x, tb, g2 + l * D, be2 + l * D, xb);
    }

    predict_k<<<NREL, 256, 0, stream>>>(x, pw, pb, (float*)d_out);
    (void)in_sizes; (void)n_in; (void)out_size; (void)ws_size;
}

// Round 4
// 711.709 us; speedup vs baseline: 8.8002x; 1.2815x over previous
//
#include <hip/hip_runtime.h>

// Codred forward. R3:
//  - attention rewritten as flash-decoding: NS=3 KV-chunks per (qtile,head),
//    grid 600 blocks (was 200), unnormalized bf16 partials + (m,l), combine kernel
//  - reg-staged double buffer for K/V tiles (issue-early / write-late)
//  - Vt pad 76 (no XOR swizzle) -> conflict-free PV reads; s_setprio around MFMA
//  - partial buffers alias tb+fb (dead during attention), ml aliases span part buf

#define D    768
#define H    8
#define DKD  96
#define LAY  4
#define FFD  1024
#define NREL 97
#define BAG  8
#define SPANS 5
#define E    40
#define TT   1600
#define SEQ  512
#define D3   2304   // fused qkv width
#define NS   3      // kv chunks

typedef __attribute__((ext_vector_type(8))) short bf16x8;
typedef __attribute__((ext_vector_type(4))) float f32x4;
typedef unsigned short ushort_t;
typedef unsigned int uint_t;

__device__ __forceinline__ ushort_t f2b(float x) {
    uint_t u = __builtin_bit_cast(uint_t, x);
    return (ushort_t)((u + 0x7fffu + ((u >> 16) & 1u)) >> 16);   // RNE
}
__device__ __forceinline__ float b2f(ushort_t v) {
    return __builtin_bit_cast(float, (uint_t)v << 16);
}

__device__ __forceinline__ void gload16(const void* g, void* l) {
    __builtin_amdgcn_global_load_lds(
        (const __attribute__((address_space(1))) unsigned int*)g,
        (__attribute__((address_space(3))) unsigned int*)l, 16, 0, 0);
}

// ---------------- block reductions (256 thr) --------------------------------
__device__ __forceinline__ float block_sum(float v, float* red) {
#pragma unroll
    for (int o = 32; o >= 1; o >>= 1) v += __shfl_xor(v, o);
    __syncthreads();
    if ((threadIdx.x & 63) == 0) red[threadIdx.x >> 6] = v;
    __syncthreads();
    return red[0] + red[1] + red[2] + red[3];
}

// ---------------- span max-pool, phase 1: per 64-position group -------------
__global__ __launch_bounds__(256) void span_pool_p1(const float* __restrict__ emb,
        const int* __restrict__ spans, float* __restrict__ partial) {
    const int e = blockIdx.x, pg = blockIdx.y;
    const int bag = e / SPANS;
    const int st = spans[e * 2 + 0];
    const int en = spans[e * 2 + 1];
    const int p0 = max(st, pg * 64);
    const int p1 = min(en, pg * 64 + 63);
    const int tid = threadIdx.x;
    if (tid >= 192) return;
    float4 m = make_float4(-1e30f, -1e30f, -1e30f, -1e30f);
    for (int p = p0; p <= p1; ++p) {
        const float4 v = *(const float4*)(emb + ((size_t)bag * SEQ + p) * D + tid * 4);
        m.x = fmaxf(m.x, v.x); m.y = fmaxf(m.y, v.y);
        m.z = fmaxf(m.z, v.z); m.w = fmaxf(m.w, v.w);
    }
    *(float4*)(partial + ((size_t)e * 8 + pg) * D + tid * 4) = m;
}

// ---------------- span max-pool, phase 2: reduce 8 partials ------------------
__global__ __launch_bounds__(256) void span_pool_p2(const float* __restrict__ partial,
        float* __restrict__ htb) {
    const int e = blockIdx.x;
    const int tid = threadIdx.x;
    if (tid >= 192) return;
    float4 m = make_float4(-1e30f, -1e30f, -1e30f, -1e30f);
#pragma unroll
    for (int pg = 0; pg < 8; ++pg) {
        const float4 v = *(const float4*)(partial + ((size_t)e * 8 + pg) * D + tid * 4);
        m.x = fmaxf(m.x, v.x); m.y = fmaxf(m.y, v.y);
        m.z = fmaxf(m.z, v.z); m.w = fmaxf(m.w, v.w);
    }
    *(float4*)(htb + (size_t)e * D + tid * 4) = m;
}

// ---------------- alpha (bf16 out) ------------------------------------------
__global__ __launch_bounds__(256) void alpha_k(const float* __restrict__ u,
        const float* __restrict__ v, ushort_t* __restrict__ a) {
    const int ij = blockIdx.x;
    const int i = ij / E, j = ij % E;
    const int tid = threadIdx.x;
#pragma unroll
    for (int t2 = 0; t2 < 3; ++t2) {
        const int d = tid + t2 * 256;
        a[(size_t)ij * D + d] = f2b(fmaxf(u[(size_t)i * D + d] + v[(size_t)j * D + d], 0.f));
    }
}

// ---------------- fp32 GEMM for u,v (M=40), fused via blockIdx.z ------------
__global__ __launch_bounds__(256) void gemm_uv(const float* __restrict__ A,
        const float* __restrict__ B0, const float* __restrict__ bias0, float* __restrict__ C0,
        const float* __restrict__ B1, const float* __restrict__ bias1, float* __restrict__ C1,
        int M, int N, int K) {
    const float* B = blockIdx.z ? B1 : B0;
    const float* bias = blockIdx.z ? bias1 : bias0;
    float* C = blockIdx.z ? C1 : C0;
    __shared__ float As[16][68];
    __shared__ float Bs[16][68];
    const int bn = blockIdx.x * 64;
    const int bm = blockIdx.y * 64;
    const int tid = threadIdx.x;
    const int tx = tid & 15;
    const int ty = tid >> 4;
    const int ar = tid >> 2;
    const int ac = (tid & 3) << 2;
    const int br = tid >> 4;
    const int bc = (tid & 15) << 2;
    float acc[4][4] = {};
    for (int k0 = 0; k0 < K; k0 += 16) {
        float4 av;
        if (bm + ar < M) av = *(const float4*)(A + (size_t)(bm + ar) * K + k0 + ac);
        else             av = make_float4(0.f, 0.f, 0.f, 0.f);
        const float4 bv = *(const float4*)(B + (size_t)(k0 + br) * N + bn + bc);
        As[ac + 0][ar] = av.x; As[ac + 1][ar] = av.y;
        As[ac + 2][ar] = av.z; As[ac + 3][ar] = av.w;
        *(float4*)&Bs[br][bc] = bv;
        __syncthreads();
#pragma unroll
        for (int kk = 0; kk < 16; ++kk) {
            const float4 a = *(const float4*)&As[kk][ty << 2];
            const float4 b = *(const float4*)&Bs[kk][tx << 2];
            acc[0][0] += a.x * b.x; acc[0][1] += a.x * b.y; acc[0][2] += a.x * b.z; acc[0][3] += a.x * b.w;
            acc[1][0] += a.y * b.x; acc[1][1] += a.y * b.y; acc[1][2] += a.y * b.z; acc[1][3] += a.y * b.w;
            acc[2][0] += a.z * b.x; acc[2][1] += a.z * b.y; acc[2][2] += a.z * b.z; acc[2][3] += a.z * b.w;
            acc[3][0] += a.w * b.x; acc[3][1] += a.w * b.y; acc[3][2] += a.w * b.z; acc[3][3] += a.w * b.w;
        }
        __syncthreads();
    }
#pragma unroll
    for (int i = 0; i < 4; ++i) {
        const int row = bm + (ty << 2) + i;
        if (row >= M) continue;
#pragma unroll
        for (int j = 0; j < 4; ++j) {
            const int col = bn + (tx << 2) + j;
            C[(size_t)row * N + col] = acc[i][j] + bias[col];
        }
    }
}

// ---------------- weight transpose+cast: src f32 [K][N] -> dst bf16 [N][K] --
__global__ __launch_bounds__(256) void transpose_cast(const float* __restrict__ S0,
        const float* __restrict__ S1, const float* __restrict__ S2,
        const float* __restrict__ S3, ushort_t* __restrict__ dst, int K, int N) {
    __shared__ float t[32][33];
    const float* src = (blockIdx.z == 0) ? S0 : (blockIdx.z == 1) ? S1 :
                       (blockIdx.z == 2) ? S2 : S3;
    ushort_t* d = dst + (size_t)blockIdx.z * K * N;
    const int n0 = blockIdx.x * 32, k0 = blockIdx.y * 32;
    const int tx = threadIdx.x & 31, ty = threadIdx.x >> 5;
#pragma unroll
    for (int i = 0; i < 4; ++i)
        t[ty + i * 8][tx] = src[(size_t)(k0 + ty + i * 8) * N + n0 + tx];
    __syncthreads();
#pragma unroll
    for (int i = 0; i < 4; ++i)
        d[(size_t)(n0 + ty + i * 8) * K + k0 + tx] = f2b(t[tx][ty + i * 8]);
}

// ---------------- concat qkv bias: [L][2304] ---------------------------------
__global__ __launch_bounds__(256) void concat_bias(const float* __restrict__ bq,
        const float* __restrict__ bk, const float* __restrict__ bv,
        float* __restrict__ dst) {
    const int i = blockIdx.x * 256 + threadIdx.x;
    if (i >= LAY * D3) return;
    const int l = i / D3, j = i % D3;
    float v;
    if (j < D) v = bq[l * D + j];
    else if (j < 2 * D) v = bk[l * D + j - D];
    else v = bv[l * D + j - 2 * D];
    dst[i] = v;
}

// ---------------- bf16 MFMA GEMM: C = A[M,K] @ Bt[N,K]^T + bias -------------
template<int RELU>
__global__ __launch_bounds__(256) void gemm_mfma(const ushort_t* __restrict__ A,
        const ushort_t* __restrict__ Bt, const float* __restrict__ bias,
        float* __restrict__ Cf, ushort_t* __restrict__ Cb, int M, int N, int K) {
    __shared__ ushort_t As[128 * 32];   // linear: row*32 + col
    __shared__ ushort_t Bs[64 * 32];
    const int tid = threadIdx.x;
    const int lane = tid & 63, w = tid >> 6;
    const int l15 = lane & 15, lg = lane >> 4;
    const int bm = blockIdx.y * 128, bn = blockIdx.x * 64;
    const int wm = (w >> 1) * 64, wn = (w & 1) * 32;
    const int trA0 = w * 32 + (lane >> 2);
    const int trA1 = trA0 + 16;
    const int trB  = w * 16 + (lane >> 2);
    const int sc   = (lane & 3) * 8;
    const size_t rowA0 = (size_t)min(bm + trA0, M - 1) * K;
    const size_t rowA1 = (size_t)min(bm + trA1, M - 1) * K;
    const size_t rowB  = (size_t)(bn + trB) * K;
    ushort_t* asd0 = As + w * 1024;
    ushort_t* asd1 = As + w * 1024 + 512;
    ushort_t* bsd  = Bs + w * 512;

    f32x4 acc[4][2];
#pragma unroll
    for (int mi = 0; mi < 4; ++mi)
#pragma unroll
        for (int ni = 0; ni < 2; ++ni)
            acc[mi][ni] = (f32x4){0.f, 0.f, 0.f, 0.f};

    for (int k0 = 0; k0 < K; k0 += 32) {
        __syncthreads();
        gload16(A + rowA0 + k0 + sc, asd0);
        gload16(A + rowA1 + k0 + sc, asd1);
        gload16(Bt + rowB + k0 + sc, bsd);
        __syncthreads();
        bf16x8 af[4], bfr[2];
#pragma unroll
        for (int mi = 0; mi < 4; ++mi)
            af[mi] = *(const bf16x8*)&As[(wm + mi * 16 + l15) * 32 + lg * 8];
#pragma unroll
        for (int ni = 0; ni < 2; ++ni)
            bfr[ni] = *(const bf16x8*)&Bs[(wn + ni * 16 + l15) * 32 + lg * 8];
        __builtin_amdgcn_s_setprio(1);
#pragma unroll
        for (int mi = 0; mi < 4; ++mi)
#pragma unroll
            for (int ni = 0; ni < 2; ++ni)
                acc[mi][ni] = __builtin_amdgcn_mfma_f32_16x16x32_bf16(
                    af[mi], bfr[ni], acc[mi][ni], 0, 0, 0);
        __builtin_amdgcn_s_setprio(0);
    }
#pragma unroll
    for (int mi = 0; mi < 4; ++mi)
#pragma unroll
        for (int ni = 0; ni < 2; ++ni)
#pragma unroll
            for (int r = 0; r < 4; ++r) {
                const int row = bm + wm + mi * 16 + lg * 4 + r;
                if (row >= M) continue;
                const int col = bn + wn + ni * 16 + l15;
                float v = acc[mi][ni][r] + bias[col];
                if (RELU) v = fmaxf(v, 0.f);
                if (Cf) Cf[(size_t)row * N + col] = v;
                if (Cb) Cb[(size_t)row * N + col] = f2b(v);
            }
}

// ---------------- flash-decoding attention, partial over a KV chunk ---------
// grid (25 qtiles, 8 heads, NS chunks); block 256 = 4 waves, wave w owns
// 16 q-rows. Emits unnormalized O (bf16) + per-(row,head) (m,l) fp32.
__global__ __launch_bounds__(256) void attn_part(const ushort_t* __restrict__ Q,
        const ushort_t* __restrict__ K, const ushort_t* __restrict__ V,
        ushort_t* __restrict__ Opart, float* __restrict__ ml, int ldin) {
    __shared__ ushort_t Qs[64][104];     // 96 + 8 pad
    __shared__ ushort_t Ks[64][104];
    __shared__ ushort_t Vt[96][76];      // transposed V, +4 pad: 38-dword rows
    __shared__ ushort_t Ps[4][16][72];   // per-wave P tile
    const int q0 = blockIdx.x * 64;
    const int h = blockIdx.y;
    const int cch = blockIdx.z;
    const int t_lo = (cch * (TT / 64)) / NS;
    const int t_hi = ((cch + 1) * (TT / 64)) / NS;
    const int tid = threadIdx.x;
    const int lane = tid & 63, w = tid >> 6;
    const int l15 = lane & 15, lg = lane >> 4;
    const float scale = 0.10206207261596577f;   // 1/sqrt(96)

    // per-thread staging coords (3 chunks of 8 ushorts = 64 rows x 96 dims)
    int r_[3], c_[3];
#pragma unroll
    for (int i = 0; i < 3; ++i) {
        const int ch = i * 256 + tid;
        r_[i] = ch / 12; c_[i] = (ch % 12) * 8;
    }
    // stage Q tile
#pragma unroll
    for (int i = 0; i < 3; ++i) {
        const uint4 v4 = *(const uint4*)(Q + (size_t)(q0 + r_[i]) * ldin + h * DKD + c_[i]);
        *(uint4*)&Qs[r_[i]][c_[i]] = v4;
    }
    // prologue: load first K/V tile into regs
    uint4 kreg[3], vreg[3];
    {
        const int s0 = t_lo * 64;
#pragma unroll
        for (int i = 0; i < 3; ++i) {
            kreg[i] = *(const uint4*)(K + (size_t)(s0 + r_[i]) * ldin + h * DKD + c_[i]);
            vreg[i] = *(const uint4*)(V + (size_t)(s0 + r_[i]) * ldin + h * DKD + c_[i]);
        }
    }
    float m_run[4], l_run[4];
    f32x4 acc_o[6];
#pragma unroll
    for (int r = 0; r < 4; ++r) { m_run[r] = -1e30f; l_run[r] = 0.f; }
#pragma unroll
    for (int nt = 0; nt < 6; ++nt) acc_o[nt] = (f32x4){0.f, 0.f, 0.f, 0.f};

    for (int t = t_lo; t < t_hi; ++t) {
        __syncthreads();   // prev compute done reading LDS; Q staged (1st iter)
#pragma unroll
        for (int i = 0; i < 3; ++i) {
            *(uint4*)&Ks[r_[i]][c_[i]] = kreg[i];
            const ushort_t* pv = (const ushort_t*)&vreg[i];
#pragma unroll
            for (int j = 0; j < 8; ++j) Vt[c_[i] + j][r_[i]] = pv[j];
        }
        __syncthreads();
        if (t + 1 < t_hi) {            // issue next-tile loads early (T14)
            const int s0 = (t + 1) * 64;
#pragma unroll
            for (int i = 0; i < 3; ++i) {
                kreg[i] = *(const uint4*)(K + (size_t)(s0 + r_[i]) * ldin + h * DKD + c_[i]);
                vreg[i] = *(const uint4*)(V + (size_t)(s0 + r_[i]) * ldin + h * DKD + c_[i]);
            }
        }
        // S = Q K^T
        f32x4 accs[4];
#pragma unroll
        for (int ni = 0; ni < 4; ++ni) accs[ni] = (f32x4){0.f, 0.f, 0.f, 0.f};
        __builtin_amdgcn_s_setprio(1);
#pragma unroll
        for (int ks = 0; ks < 3; ++ks) {
            const bf16x8 aq = *(const bf16x8*)&Qs[w * 16 + l15][ks * 32 + lg * 8];
#pragma unroll
            for (int ni = 0; ni < 4; ++ni) {
                const bf16x8 bk = *(const bf16x8*)&Ks[ni * 16 + l15][ks * 32 + lg * 8];
                accs[ni] = __builtin_amdgcn_mfma_f32_16x16x32_bf16(aq, bk, accs[ni], 0, 0, 0);
            }
        }
        __builtin_amdgcn_s_setprio(0);
        // online softmax
        float ps[4][4];
#pragma unroll
        for (int r = 0; r < 4; ++r) {
#pragma unroll
            for (int ni = 0; ni < 4; ++ni) ps[ni][r] = accs[ni][r] * scale;
            float mx = fmaxf(fmaxf(ps[0][r], ps[1][r]), fmaxf(ps[2][r], ps[3][r]));
#pragma unroll
            for (int o = 1; o <= 8; o <<= 1) mx = fmaxf(mx, __shfl_xor(mx, o));
            const float mnew = fmaxf(m_run[r], mx);
            const float sf = __expf(m_run[r] - mnew);
            m_run[r] = mnew;
            float rs = 0.f;
#pragma unroll
            for (int ni = 0; ni < 4; ++ni) {
                ps[ni][r] = __expf(ps[ni][r] - mnew);
                rs += ps[ni][r];
            }
#pragma unroll
            for (int o = 1; o <= 8; o <<= 1) rs += __shfl_xor(rs, o);
            l_run[r] = l_run[r] * sf + rs;
#pragma unroll
            for (int nt = 0; nt < 6; ++nt) acc_o[nt][r] *= sf;
        }
#pragma unroll
        for (int ni = 0; ni < 4; ++ni)
#pragma unroll
            for (int r = 0; r < 4; ++r)
                Ps[w][lg * 4 + r][ni * 16 + l15] = f2b(ps[ni][r]);
        // O += P @ V
        __builtin_amdgcn_s_setprio(1);
#pragma unroll
        for (int ks = 0; ks < 2; ++ks) {
            const bf16x8 ap = *(const bf16x8*)&Ps[w][l15][ks * 32 + lg * 8];
#pragma unroll
            for (int nt = 0; nt < 6; ++nt) {
                const bf16x8 bv = *(const bf16x8*)&Vt[nt * 16 + l15][ks * 32 + lg * 8];
                acc_o[nt] = __builtin_amdgcn_mfma_f32_16x16x32_bf16(ap, bv, acc_o[nt], 0, 0, 0);
            }
        }
        __builtin_amdgcn_s_setprio(0);
    }
    // epilogue: unnormalized O + (m,l)
#pragma unroll
    for (int nt = 0; nt < 6; ++nt)
#pragma unroll
        for (int r = 0; r < 4; ++r) {
            const int row = q0 + w * 16 + lg * 4 + r;
            const int col = h * DKD + nt * 16 + l15;
            Opart[((size_t)cch * TT + row) * D + col] = f2b(acc_o[nt][r]);
        }
    if (l15 == 0) {
#pragma unroll
        for (int r = 0; r < 4; ++r) {
            const int row = q0 + w * 16 + lg * 4 + r;
            float2* mlp = (float2*)ml;
            mlp[((size_t)cch * H + h) * TT + row] = make_float2(m_run[r], l_run[r]);
        }
    }
}

// ---------------- combine NS partials per row -------------------------------
__global__ __launch_bounds__(256) void attn_combine(const ushort_t* __restrict__ Opart,
        const float* __restrict__ ml, ushort_t* __restrict__ O) {
    const int row = blockIdx.x;
    const int tid = threadIdx.x;
    const float2* mlp = (const float2*)ml;
#pragma unroll
    for (int kk = 0; kk < 3; ++kk) {
        const int col = tid + kk * 256;
        const int h = col / DKD;
        float m[NS], l[NS], M = -1e30f;
#pragma unroll
        for (int c = 0; c < NS; ++c) {
            const float2 v = mlp[((size_t)c * H + h) * TT + row];
            m[c] = v.x; l[c] = v.y; M = fmaxf(M, m[c]);
        }
        float L = 0.f, o = 0.f;
#pragma unroll
        for (int c = 0; c < NS; ++c) {
            const float e = __expf(m[c] - M);
            L += l[c] * e;
            o += b2f(Opart[((size_t)c * TT + row) * D + col]) * e;
        }
        O[(size_t)row * D + col] = f2b(o / L);
    }
}

// ---------------- x = LN(x + y); writes fp32 x and bf16 xb ------------------
__global__ __launch_bounds__(256) void add_ln(float* __restrict__ x,
        const float* __restrict__ y, const float* __restrict__ g,
        const float* __restrict__ b, ushort_t* __restrict__ xb) {
    __shared__ float red[4];
    const int row = blockIdx.x;
    const int tid = threadIdx.x;
    float vals[3];
    float s = 0.f;
#pragma unroll
    for (int i = 0; i < 3; ++i) {
        const int c = tid + i * 256;
        const float t = x[(size_t)row * D + c] + y[(size_t)row * D + c];
        vals[i] = t; s += t;
    }
    const float mean = block_sum(s, red) * (1.f / 768.f);
    float s2 = 0.f;
#pragma unroll
    for (int i = 0; i < 3; ++i) { const float dd = vals[i] - mean; s2 += dd * dd; }
    const float var = block_sum(s2, red) * (1.f / 768.f);
    const float inv = rsqrtf(var + 1e-5f);
#pragma unroll
    for (int i = 0; i < 3; ++i) {
        const int c = tid + i * 256;
        const float o = (vals[i] - mean) * inv * g[c] + b[c];
        x[(size_t)row * D + c] = o;
        xb[(size_t)row * D + c] = f2b(o);
    }
}

// ---------------- predictor -------------------------------------------------
__global__ __launch_bounds__(256) void predict_k(const float* __restrict__ x,
        const float* __restrict__ pw, const float* __restrict__ pb,
        float* __restrict__ out) {
    __shared__ float red[4];
    const int r = blockIdx.x;
    const int tid = threadIdx.x;
    float best = -1e30f;
    for (int bag = 0; bag < BAG; ++bag) {
        const int row = (bag * SPANS) * E + (bag * SPANS + 1);
        const float* f = x + (size_t)row * D;
        float acc = 0.f;
        for (int d = tid; d < D; d += 256) acc += f[d] * pw[(size_t)d * NREL + r];
        best = fmaxf(best, block_sum(acc, red));
    }
    if (tid == 0) out[r] = best + pb[r];
}

extern "C" void kernel_launch(void* const* d_in, const int* in_sizes, int n_in,
                              void* d_out, int out_size, void* d_ws, size_t ws_size,
                              hipStream_t stream) {
    const float* emb  = (const float*)d_in[0];
    const int*  spans = (const int*)d_in[1];
    const float* wu_w = (const float*)d_in[2];  const float* wu_b = (const float*)d_in[3];
    const float* wvv_w= (const float*)d_in[4];  const float* wvv_b= (const float*)d_in[5];
    const float* lnr_w= (const float*)d_in[6];  const float* lnr_b= (const float*)d_in[7];
    const float* wq = (const float*)d_in[8];    const float* bq = (const float*)d_in[9];
    const float* wk = (const float*)d_in[10];   const float* bk = (const float*)d_in[11];
    const float* wv = (const float*)d_in[12];   const float* bv = (const float*)d_in[13];
    const float* wo = (const float*)d_in[14];   const float* bo = (const float*)d_in[15];
    const float* w1 = (const float*)d_in[16];   const float* b1 = (const float*)d_in[17];
    const float* w2 = (const float*)d_in[18];   const float* b2 = (const float*)d_in[19];
    const float* g1 = (const float*)d_in[20];   const float* be1= (const float*)d_in[21];
    const float* g2 = (const float*)d_in[22];   const float* be2= (const float*)d_in[23];
    const float* pw = (const float*)d_in[24];   const float* pb = (const float*)d_in[25];

    // workspace layout (~36 MB). tb and fb MUST be adjacent: Opart aliases them.
    char* cur = (char*)d_ws;
    auto alloc = [&](size_t bytes) { char* p = cur; cur += (bytes + 255) & ~(size_t)255; return p; };
    float*    htb  = (float*)alloc(E * D * 4);
    float*    ub   = (float*)alloc(E * D * 4);
    float*    vb   = (float*)alloc(E * D * 4);
    float*    part = (float*)alloc((size_t)E * 8 * D * 4);   // span partials; reused as ml
    float*    x    = (float*)alloc((size_t)TT * D * 4);
    ushort_t* xb   = (ushort_t*)alloc((size_t)TT * D * 2);
    ushort_t* qkv  = (ushort_t*)alloc((size_t)TT * D3 * 2);
    ushort_t* ob   = (ushort_t*)alloc((size_t)TT * D * 2);   // alpha, then attn out
    float*    tb   = (float*)alloc((size_t)TT * D * 4);      // adjacent ...
    ushort_t* fb   = (ushort_t*)alloc((size_t)TT * FFD * 2); // ... to tb
    ushort_t* lnrT = (ushort_t*)alloc((size_t)D * D * 2);
    ushort_t* wT4  = (ushort_t*)alloc((size_t)4 * D * D * 2);
    ushort_t* w1T  = (ushort_t*)alloc((size_t)D * FFD * 2);
    ushort_t* w2T  = (ushort_t*)alloc((size_t)FFD * D * 2);
    float*    bqkv = (float*)alloc((size_t)LAY * D3 * 4);
    ushort_t* Opart = (ushort_t*)tb;    // NS*TT*D*2 = 7.37 MB <= tb+fb (8.19 MB)
    float*    ml    = part;             // NS*H*TT*2*4 = 300 KB <= part (983 KB)

    const int DD = D * D;

    span_pool_p1<<<dim3(E, 8), 256, 0, stream>>>(emb, spans, part);
    span_pool_p2<<<E, 256, 0, stream>>>(part, htb);
    gemm_uv<<<dim3(D / 64, 1, 2), 256, 0, stream>>>(htb, wu_w, wu_b, ub, wvv_w, wvv_b, vb, E, D, D);
    alpha_k<<<TT, 256, 0, stream>>>(ub, vb, ob);
    transpose_cast<<<dim3(D / 32, D / 32, 1), 256, 0, stream>>>(lnr_w, lnr_w, lnr_w, lnr_w, lnrT, D, D);
    concat_bias<<<(LAY * D3 + 255) / 256, 256, 0, stream>>>(bq, bk, bv, bqkv);
    gemm_mfma<1><<<dim3(D / 64, (TT + 127) / 128), 256, 0, stream>>>(ob, lnrT, lnr_b, x, xb, TT, D, D);

    for (int l = 0; l < LAY; ++l) {
        transpose_cast<<<dim3(D / 32, D / 32, 4), 256, 0, stream>>>(
            wq + (size_t)l * DD, wk + (size_t)l * DD, wv + (size_t)l * DD, wo + (size_t)l * DD, wT4, D, D);
        transpose_cast<<<dim3(FFD / 32, D / 32, 1), 256, 0, stream>>>(
            w1 + (size_t)l * D * FFD, w1, w1, w1, w1T, D, FFD);
        transpose_cast<<<dim3(D / 32, FFD / 32, 1), 256, 0, stream>>>(
            w2 + (size_t)l * FFD * D, w2, w2, w2, w2T, FFD, D);

        gemm_mfma<0><<<dim3(D3 / 64, (TT + 127) / 128), 256, 0, stream>>>(
            xb, wT4, bqkv + l * D3, nullptr, qkv, TT, D3, D);
        attn_part<<<dim3(TT / 64, H, NS), 256, 0, stream>>>(
            qkv, qkv + D, qkv + 2 * D, Opart, ml, D3);
        attn_combine<<<TT, 256, 0, stream>>>(Opart, ml, ob);
        gemm_mfma<0><<<dim3(D / 64, (TT + 127) / 128), 256, 0, stream>>>(
            ob, wT4 + 3 * DD, bo + l * D, tb, nullptr, TT, D, D);
        add_ln<<<TT, 256, 0, stream>>>(x, tb, g1 + l * D, be1 + l * D, xb);
        gemm_mfma<1><<<dim3(FFD / 64, (TT + 127) / 128), 256, 0, stream>>>(
            xb, w1T, b1 + l * FFD, nullptr, fb, TT, FFD, D);
        gemm_mfma<0><<<dim3(D / 64, (TT + 127) / 128), 256, 0, stream>>>(
            fb, w2T, b2 + l * D, tb, nullptr, TT, D, FFD);
        add_ln<<<TT, 256, 0, stream>>>(x, tb, g2 + l * D, be2 + l * D, xb);
    }

    predict_k<<<NREL, 256, 0, stream>>>(x, pw, pb, (float*)d_out);
    (void)in_sizes; (void)n_in; (void)out_size; (void)ws_size;
}